// Round 3
// baseline (270.180 us; speedup 1.0000x reference)
//
#include <hip/hip_runtime.h>
#include <hip/hip_bf16.h>

// USR_EMB: out[b,h,:] = emb_usr[searchsorted(userlist, x[b,h]), :]
// EMB = 64 floats = 16 float4 = 256 B per row. Table = 100001 rows = 25.6 MB.
//
// R7: id-range partitioning onto XCDs.
//   Old scheme: every XCD gathers from the whole 25.6 MB table -> ~84% of
//   gathers miss the 4 MB per-XCD L2, each row is pulled into ~6 different
//   L2s (~150 MB cross-fabric random reads) while the 210 MB output stream
//   thrashes the memory-side L3. Kernel ~123 us at ~3.4 TB/s effective.
//   New scheme: ids are split into NXCD=8 ranges (~12.5K ids = 3.2 MB of
//   rows, fits one 4 MB L2). Block b handles range c = b%8; round-robin
//   dispatch places those blocks on XCD c (perf heuristic only - correctness
//   does not depend on the mapping). Each range-c block scans a 2048-elem
//   chunk of x (8x re-scan of a 3.3 MB L3-resident buffer = cheap), compacts
//   in-range elements into an LDS queue (ballot + prefix popcount), then
//   copies rows wave-cooperatively (16 lanes per 256 B row). Each emb row is
//   read by exactly one XCD: HBM table reads drop to the 25.6 MB compulsory
//   minimum; the 8.2x reuse becomes per-XCD L2 hits.
//   nt stores kept (no "memory" clobber so loads still batch): they keep the
//   per-XCD write stream (26 MB/XCD) from evicting the 3.2 MB slice in L2.
//
// Phase-1 lookup unchanged: interpolation probe (one load) with binary-search
//   fallback for any sorted unique userlist.

#define V4_PER_ROW 16       // 64 floats / 4
#define ELEMS_PER_BLOCK 2048
#define NXCD 8

typedef float f32x4 __attribute__((ext_vector_type(4)));

__device__ __forceinline__ void store_nt_f4(f32x4* p, f32x4 v)
{
    // %0 = address (VGPR pair), %1 = data (VGPR quad). No "memory" clobber:
    // out is never read by this kernel, and dropping it lets the compiler
    // keep multiple gather loads in flight across stores.
    asm volatile("global_store_dwordx4 %0, %1, off nt"
                 :
                 : "v"(p), "v"(v));
}

__global__ __launch_bounds__(256) void usr_emb_gather(
    const int* __restrict__ x,
    const int* __restrict__ userlist, int n_user,
    const float* __restrict__ emb,
    float* __restrict__ out,
    int n_elem)
{
    __shared__ int q_id[ELEMS_PER_BLOCK];
    __shared__ int q_ge[ELEMS_PER_BLOCK];
    __shared__ int q_count;

    const int t    = threadIdx.x;
    const int lane = t & 63;
    const int wave = t >> 6;

    const int c  = blockIdx.x & (NXCD - 1);   // id-range (-> XCD via round-robin)
    const int j  = blockIdx.x >> 3;           // chunk index within the x scan
    const int e0 = j * ELEMS_PER_BLOCK;

    // id-range owned by this block's XCD
    const int rs    = (n_user + NXCD - 1) >> 3;
    const int lo_id = c * rs;
    const int hi_id = min(lo_id + rs, n_user);

    if (t == 0) q_count = 0;
    __syncthreads();

    const int v1 = userlist[1];               // wave-uniform, L1-hit

    // ---- Phase A: scan 2048 elements, queue the in-range ones ----
#pragma unroll
    for (int r = 0; r < 2; ++r) {
        const int base = e0 + r * 1024 + t * 4;
        int  u[4];
        bool valid[4];
        if (base + 3 < n_elem) {
            const int4 xv = *(const int4*)(x + base);
            u[0] = xv.x; u[1] = xv.y; u[2] = xv.z; u[3] = xv.w;
            valid[0] = valid[1] = valid[2] = valid[3] = true;
        } else {
#pragma unroll
            for (int k = 0; k < 4; ++k) {
                valid[k] = (base + k) < n_elem;
                u[k]     = valid[k] ? x[base + k] : 0;
            }
        }
#pragma unroll
        for (int k = 0; k < 4; ++k) {
            int  id   = 0;
            bool flag = false;
            if (valid[k]) {
                int g = 1 + (u[k] - v1);                  // interpolation probe
                bool hit = (g >= 1 && g < n_user) && (userlist[g] == u[k]);
                if (!hit) {                               // lower_bound fallback
                    int lo = 0, hi = n_user;
                    while (lo < hi) {
                        const int mid = (lo + hi) >> 1;
                        if (userlist[mid] < u[k]) lo = mid + 1;
                        else                      hi = mid;
                    }
                    g = lo;
                }
                id   = g;
                flag = (id >= lo_id) && (id < hi_id);
            }
            const unsigned long long m = __ballot(flag);
            if (m) {
                int pos = 0;
                if (lane == 0) pos = atomicAdd(&q_count, __popcll(m));
                pos = __shfl(pos, 0);
                pos += __popcll(m & ((1ull << lane) - 1ull));
                if (flag) {
                    q_id[pos] = id;
                    q_ge[pos] = base + k;
                }
            }
        }
    }
    __syncthreads();

    // ---- Phase B: wave-cooperative row copy (16 lanes per 256 B row) ----
    const int count = q_count;
    const f32x4* __restrict__ emb4 = (const f32x4*)emb;
    f32x4*       __restrict__ out4 = (f32x4*)out;

    const int sub   = lane & (V4_PER_ROW - 1);  // float4 index within row
    const int eslot = lane >> 4;                // 0..3: which queued entry

    for (int i = wave * 4 + eslot; i < count; i += 16) {
        const int id = q_id[i];                 // 16-lane broadcast read
        const int ge = q_ge[i];
        const f32x4 row = emb4[(size_t)id * V4_PER_ROW + sub];
        store_nt_f4(&out4[(size_t)ge * V4_PER_ROW + sub], row);
    }
}

extern "C" void kernel_launch(void* const* d_in, const int* in_sizes, int n_in,
                              void* d_out, int out_size, void* d_ws, size_t ws_size,
                              hipStream_t stream) {
    const int*   x        = (const int*)d_in[0];    // [BATCH*HIST] indices
    const int*   userlist = (const int*)d_in[1];    // [USR_SIZE+1] sorted ids
    const float* emb      = (const float*)d_in[2];  // [USR_SIZE+1, 64]
    float*       out      = (float*)d_out;          // [BATCH*HIST, 64]

    const int n_elem = in_sizes[0];                 // 819200
    const int n_user = in_sizes[1];                 // 100001

    const int chunks = (n_elem + ELEMS_PER_BLOCK - 1) / ELEMS_PER_BLOCK;  // 400
    const int blocks = chunks * NXCD;                                     // 3200
    usr_emb_gather<<<blocks, 256, 0, stream>>>(x, userlist, n_user, emb, out, n_elem);
}

// Round 4
// 255.871 us; speedup vs baseline: 1.0559x; 1.0559x over previous
//
#include <hip/hip_runtime.h>
#include <hip/hip_bf16.h>
#include <limits.h>

// USR_EMB: out[b,h,:] = emb_usr[searchsorted(userlist, x[b,h]), :]
// EMB = 64 floats = 16 float4 = 256 B per row. Table = 100001 rows = 25.6 MB.
//
// R8: id-range partitioning (R7) FIXED on both legs that nulled it:
//  (1) Stores now use the TRUE gfx95x streaming encoding `nt sc0 sc1`
//      (what __builtin_nontemporal_store lowers to on gfx940+). R7's
//      `nt`-only stores still write-ALLOCATED in L2, so each XCD's 26 MB
//      output stream evicted the 3.2 MB table slice the partitioning was
//      meant to pin in its 4 MB L2 — the hypothesis was never tested.
//  (2) Range-membership binning without searchsorted: for sorted userlist,
//      id in [lo,hi)  <=>  userlist[lo-1] < u <= userlist[hi-1]
//      (two wave-uniform scalar compares). The real probe runs only for
//      queued (in-range) elements, so total lookups = n_elem — R7's 8x
//      redundant lookup overhead is gone. Remaining redundancy: 8x re-read
//      of the 3.3 MB L3-resident x buffer (~4 us).
//
// Structure: block b => id-range c = b&7 (round-robin dispatch places it on
// XCD c; perf heuristic only, correctness never depends on the mapping),
// chunk j = b>>3 of 2048 elements. Phase A: scan chunk, ballot-compact
// in-range elements into an LDS queue. Phase B: wave-cooperative row copy
// (16 lanes per 256 B row), gather from the XCD-local 3.2 MB slice,
// streaming-store to out.

#define V4_PER_ROW 16       // 64 floats / 4
#define ELEMS_PER_BLOCK 2048
#define NXCD 8

typedef float f32x4 __attribute__((ext_vector_type(4)));

__device__ __forceinline__ void store_stream_f4(f32x4* p, f32x4 v)
{
    // nt sc0 sc1 = non-temporal system-scope: no L2 allocation, so the
    // output stream cannot evict the XCD-local table slice.
    asm volatile("global_store_dwordx4 %0, %1, off nt sc0 sc1"
                 :
                 : "v"(p), "v"(v));
}

__global__ __launch_bounds__(256) void usr_emb_gather(
    const int* __restrict__ x,
    const int* __restrict__ userlist, int n_user,
    const float* __restrict__ emb,
    float* __restrict__ out,
    int n_elem)
{
    __shared__ int q_id[ELEMS_PER_BLOCK];
    __shared__ int q_ge[ELEMS_PER_BLOCK];
    __shared__ int q_count;

    const int t    = threadIdx.x;
    const int lane = t & 63;
    const int wave = t >> 6;

    const int c  = blockIdx.x & (NXCD - 1);   // id-range (-> XCD via round-robin)
    const int j  = blockIdx.x >> 3;           // chunk index within the x scan
    const int e0 = j * ELEMS_PER_BLOCK;

    // id-range owned by this block's XCD
    const int rs    = (n_user + NXCD - 1) >> 3;
    const int lo_id = c * rs;
    const int hi_id = min(lo_id + rs, n_user);

    if (t == 0) q_count = 0;
    __syncthreads();

    // Range test WITHOUT searchsorted:
    //   id >= lo_id  <=>  u > userlist[lo_id-1]   (lo_id==0 => always true)
    //   id <  hi_id  <=>  u <= userlist[hi_id-1]  (hi_id >= 1 always)
    const int ul_lo = (lo_id > 0) ? userlist[lo_id - 1] : INT_MIN;
    const int ul_hi = userlist[hi_id - 1];
    const int v1    = userlist[1];            // for the interpolation probe

    // ---- Phase A: scan 2048 elements, queue the in-range ones ----
#pragma unroll
    for (int r = 0; r < 2; ++r) {
        const int base = e0 + r * 1024 + t * 4;
        int  u[4];
        bool valid[4];
        if (base + 3 < n_elem) {
            const int4 xv = *(const int4*)(x + base);
            u[0] = xv.x; u[1] = xv.y; u[2] = xv.z; u[3] = xv.w;
            valid[0] = valid[1] = valid[2] = valid[3] = true;
        } else {
#pragma unroll
            for (int k = 0; k < 4; ++k) {
                valid[k] = (base + k) < n_elem;
                u[k]     = valid[k] ? x[base + k] : 0;
            }
        }
#pragma unroll
        for (int k = 0; k < 4; ++k) {
            const bool flag = valid[k]
                              && (lo_id == 0 || u[k] > ul_lo)
                              && (u[k] <= ul_hi);
            int id = 0;
            if (flag) {                                   // probe only in-range
                int g = 1 + (u[k] - v1);                  // interpolation probe
                bool hit = (g >= 1 && g < n_user) && (userlist[g] == u[k]);
                if (!hit) {                               // lower_bound fallback
                    int lo = 0, hi = n_user;
                    while (lo < hi) {
                        const int mid = (lo + hi) >> 1;
                        if (userlist[mid] < u[k]) lo = mid + 1;
                        else                      hi = mid;
                    }
                    g = lo;
                }
                id = g;
            }
            const unsigned long long m = __ballot(flag);
            if (m) {
                int pos = 0;
                if (lane == 0) pos = atomicAdd(&q_count, __popcll(m));
                pos = __shfl(pos, 0);
                pos += __popcll(m & ((1ull << lane) - 1ull));
                if (flag) {
                    q_id[pos] = id;
                    q_ge[pos] = base + k;
                }
            }
        }
    }
    __syncthreads();

    // ---- Phase B: wave-cooperative row copy (16 lanes per 256 B row) ----
    const int count = q_count;
    const f32x4* __restrict__ emb4 = (const f32x4*)emb;
    f32x4*       __restrict__ out4 = (f32x4*)out;

    const int sub   = lane & (V4_PER_ROW - 1);  // float4 index within row
    const int eslot = lane >> 4;                // 0..3: which queued entry

    for (int i = wave * 4 + eslot; i < count; i += 16) {
        const int id = q_id[i];                 // 16-lane broadcast read
        const int ge = q_ge[i];
        const f32x4 row = emb4[(size_t)id * V4_PER_ROW + sub];
        store_stream_f4(&out4[(size_t)ge * V4_PER_ROW + sub], row);
    }
}

extern "C" void kernel_launch(void* const* d_in, const int* in_sizes, int n_in,
                              void* d_out, int out_size, void* d_ws, size_t ws_size,
                              hipStream_t stream) {
    const int*   x        = (const int*)d_in[0];    // [BATCH*HIST] indices
    const int*   userlist = (const int*)d_in[1];    // [USR_SIZE+1] sorted ids
    const float* emb      = (const float*)d_in[2];  // [USR_SIZE+1, 64]
    float*       out      = (float*)d_out;          // [BATCH*HIST, 64]

    const int n_elem = in_sizes[0];                 // 819200
    const int n_user = in_sizes[1];                 // 100001

    const int chunks = (n_elem + ELEMS_PER_BLOCK - 1) / ELEMS_PER_BLOCK;  // 400
    const int blocks = chunks * NXCD;                                     // 3200
    usr_emb_gather<<<blocks, 256, 0, stream>>>(x, userlist, n_user, emb, out, n_elem);
}